// Round 4
// baseline (418.327 us; speedup 1.0000x reference)
//
#include <hip/hip_runtime.h>
#include <math.h>

#define BB 8
#define TT 4096
#define FF 1024
#define F4 (FF / 4)        // 256 float4 per row
#define TS 128             // t-chunks per batch
#define TCHUNK (TT / TS)   // 32 timesteps per chunk

typedef float vfloat4 __attribute__((ext_vector_type(4)));

// ---------------------------------------------------------------------------
// Kernel A: partial masked column sums (valid-prefix skip) + in-kernel
// last-block reduction. Every block tickets ready[b] after storing its
// partials; the TS-th arriver for batch b reduces part -> kbuf, Sk, Skk,
// overlapping the reduction with other batches' producers (no k2 dispatch,
// no full-device drain between sum and stats).
// Cross-XCD discipline (G16): producer release = __threadfence() before the
// device-scope atomicAdd; reducer acquire = __threadfence() after the ticket
// before reading part (invalidates stale L2 lines from the poison fill).
// grid: (TS, BB), block: 256.
// ---------------------------------------------------------------------------
__global__ __launch_bounds__(256) void kA_sum_stats(const float4* __restrict__ x4,
                                                    const int* __restrict__ mask,
                                                    float4* __restrict__ part4,
                                                    float4* __restrict__ kbuf4,
                                                    float* __restrict__ Sk,
                                                    float* __restrict__ Skk,
                                                    int* __restrict__ ready) {
    const int ts   = blockIdx.x;
    const int b    = blockIdx.y;
    const int tid  = threadIdx.x;
    const int wave = tid >> 6;
    const int lane = tid & 63;

    // ---- my chunk's valid-row count (uniform address -> scalar loads) ----
    const int* mrow = mask + (size_t)b * TT + ts * TCHUNK;
    int nv = 0;
    #pragma unroll
    for (int i = 0; i < TCHUNK; ++i) nv += mrow[i];

    if (nv > 0) {
        const float4* xb = x4 + ((size_t)b * TT + (size_t)ts * TCHUNK) * F4 + tid;
        float4 acc = make_float4(0.f, 0.f, 0.f, 0.f);
        #pragma unroll 8
        for (int t = 0; t < nv; ++t) {        // prefix => plain adds
            float4 v = xb[(size_t)t * F4];
            acc.x += v.x; acc.y += v.y; acc.z += v.z; acc.w += v.w;
        }
        part4[((size_t)b * TS + ts) * F4 + tid] = acc;
    }

    // ---- ticket: last arriver for batch b becomes the reducer ----
    __threadfence();                          // release: part stores visible
    __shared__ int last;
    if (tid == 0) last = (atomicAdd(&ready[b], 1) == TS - 1);
    __syncthreads();
    if (!last) return;
    __threadfence();                          // acquire: drop stale L1/L2 lines

    // ---- valid length L ----
    int c = 0;
    #pragma unroll
    for (int i = 0; i < 16; ++i) c += mask[(size_t)b * TT + tid + 256 * i];
    float fc = (float)c;
    #pragma unroll
    for (int off = 32; off; off >>= 1) fc += __shfl_xor(fc, off);
    __shared__ float Lred[4];
    if (lane == 0) Lred[wave] = fc;
    __syncthreads();
    const float Lf  = Lred[0] + Lred[1] + Lred[2] + Lred[3];
    const int   nts = ((int)Lf + TCHUNK - 1) / TCHUNK;   // only these written

    // ---- column sums over written chunks (thread owns f4-group tid) ----
    float4 s = make_float4(0.f, 0.f, 0.f, 0.f);
    #pragma unroll 4
    for (int t = 0; t < nts; ++t) {
        float4 v = part4[((size_t)b * TS + t) * F4 + tid];
        s.x += v.x; s.y += v.y; s.z += v.z; s.w += v.w;
    }
    const float invL = 1.0f / Lf;
    float4 kv;
    kv.x = s.x * invL; kv.y = s.y * invL; kv.z = s.z * invL; kv.w = s.w * invL;
    kbuf4[(size_t)b * F4 + tid] = kv;

    // ---- Sk = sum(k), Skk = sum(k^2) ----
    float a = kv.x + kv.y + kv.z + kv.w;
    float q = kv.x * kv.x + kv.y * kv.y + kv.z * kv.z + kv.w * kv.w;
    #pragma unroll
    for (int off = 32; off; off >>= 1) {
        a += __shfl_xor(a, off);
        q += __shfl_xor(q, off);
    }
    __shared__ float Ared[4], Qred[4];
    if (lane == 0) { Ared[wave] = a; Qred[wave] = q; }
    __syncthreads();
    if (tid == 0) {
        Sk[b]  = Ared[0] + Ared[1] + Ared[2] + Ared[3];   // plain stores:
        Skk[b] = Qred[0] + Qred[1] + Qred[2] + Qred[3];   // kernel boundary flushes
    }
}

// ---------------------------------------------------------------------------
// Kernel B: gate + apply, 4 rows per wave (unchanged from R3 — measured equal
// to 1-row/wave, keeps k-row register reuse). Nontemporal out stores.
// grid: (TT/16, BB), block: 256.
// ---------------------------------------------------------------------------
__global__ __launch_bounds__(256) void kB_apply(const float4* __restrict__ x4,
                                                const int* __restrict__ mask,
                                                const float4* __restrict__ kb4,
                                                const float* __restrict__ Sk,
                                                const float* __restrict__ Skk,
                                                float4* __restrict__ out4) {
    const int wave = threadIdx.x >> 6;
    const int lane = threadIdx.x & 63;
    const int b    = blockIdx.y;
    const int rowbase = blockIdx.x * 16 + wave * 4;
    const size_t base = ((size_t)b * TT + rowbase) * F4;

    const int4 m4 = *(const int4*)(mask + (size_t)b * TT + rowbase);
    const int  nv = m4.x + m4.y + m4.z + m4.w;     // prefix => count = boundary

    for (int i = nv; i < 4; ++i) {                 // padded rows: zero, no reads
        vfloat4* orow = (vfloat4*)(out4 + base + (size_t)i * F4);
        vfloat4 z = (vfloat4)(0.f);
        #pragma unroll
        for (int j = 0; j < 4; ++j)
            __builtin_nontemporal_store(z, orow + lane + 64 * j);
    }
    if (nv == 0) return;

    const float4* krow = kb4 + (size_t)b * F4;
    float4 kv[4];
    #pragma unroll
    for (int j = 0; j < 4; ++j) kv[j] = krow[lane + 64 * j];

    const float sk = Sk[b];
    const float kd = sqrtf(fmaxf(Skk[b] - sk * sk * (1.0f / FF), 0.f));

    float4 xn[4];
    #pragma unroll
    for (int j = 0; j < 4; ++j) xn[j] = (x4 + base)[lane + 64 * j];

    for (int i = 0; i < nv; ++i) {
        float4 xv[4];
        #pragma unroll
        for (int j = 0; j < 4; ++j) xv[j] = xn[j];
        if (i + 1 < nv) {
            const float4* xrow = x4 + base + (size_t)(i + 1) * F4;
            #pragma unroll
            for (int j = 0; j < 4; ++j) xn[j] = xrow[lane + 64 * j];
        }

        float s1 = 0.f, s2 = 0.f, s3 = 0.f;
        #pragma unroll
        for (int j = 0; j < 4; ++j) {
            s1 += xv[j].x + xv[j].y + xv[j].z + xv[j].w;
            s2 = fmaf(xv[j].x, xv[j].x, fmaf(xv[j].y, xv[j].y,
                 fmaf(xv[j].z, xv[j].z, fmaf(xv[j].w, xv[j].w, s2))));
            s3 = fmaf(xv[j].x, kv[j].x, fmaf(xv[j].y, kv[j].y,
                 fmaf(xv[j].z, kv[j].z, fmaf(xv[j].w, kv[j].w, s3))));
        }
        #pragma unroll
        for (int off = 32; off; off >>= 1) {
            s1 += __shfl_xor(s1, off);
            s2 += __shfl_xor(s2, off);
            s3 += __shfl_xor(s3, off);
        }

        const float mx  = s1 * (1.0f / FF);
        const float num = s3 - mx * sk;                       // dot(x_c, k_c)
        const float qd  = sqrtf(fmaxf(s2 - s1 * s1 * (1.0f / FF), 0.f));
        const float C   = num / (qd * kd);
        const float A   = 1.0f / (1.0f + __expf(C));          // 1 - sigmoid

        vfloat4* orow = (vfloat4*)(out4 + base + (size_t)i * F4);
        #pragma unroll
        for (int j = 0; j < 4; ++j) {
            vfloat4 o;
            o.x = xv[j].x * A; o.y = xv[j].y * A;
            o.z = xv[j].z * A; o.w = xv[j].w * A;
            __builtin_nontemporal_store(o, orow + lane + 64 * j);
        }
    }
}

// ---------------------------------------------------------------------------
extern "C" void kernel_launch(void* const* d_in, const int* in_sizes, int n_in,
                              void* d_out, int out_size, void* d_ws, size_t ws_size,
                              hipStream_t stream) {
    const float* x    = (const float*)d_in[0];
    const int*   mask = (const int*)d_in[1];
    float*       out  = (float*)d_out;

    // workspace (floats): part[B*TS*F] | kbuf[B*F] | Sk[B] | Skk[B] | ready[B]
    float* part  = (float*)d_ws;
    float* kbuf  = part + (size_t)BB * TS * FF;
    float* Sk    = kbuf + (size_t)BB * FF;
    float* Skk   = Sk + BB;
    int*   ready = (int*)(Skk + BB);

    hipMemsetAsync(ready, 0, BB * sizeof(int), stream);   // tickets (ws poisoned)

    kA_sum_stats<<<dim3(TS, BB), 256, 0, stream>>>((const float4*)x, mask,
                                                   (float4*)part, (float4*)kbuf,
                                                   Sk, Skk, ready);
    kB_apply<<<dim3(TT / 16, BB), 256, 0, stream>>>((const float4*)x, mask,
                                                    (const float4*)kbuf, Sk, Skk,
                                                    (float4*)out);
}

// Round 5
// 247.511 us; speedup vs baseline: 1.6901x; 1.6901x over previous
//
#include <hip/hip_runtime.h>
#include <math.h>

#define BB 8
#define TT 4096
#define FF 1024
#define F4 (FF / 4)        // 256 float4 per row
#define TS 128             // t-chunks per batch
#define TCHUNK (TT / TS)   // 32 timesteps per chunk

typedef float vfloat4 __attribute__((ext_vector_type(4)));

// ---------------------------------------------------------------------------
// Kernel 1: masked column sums straight into ksum[b,f] via device-scope
// float atomics. No part buffer, no fences: atomics are coherent at the
// device coherence point, and the k1->k3 dispatch boundary is the acquire
// for k3's plain reads (R4 lesson: per-block __threadfence = 1024 L2
// flushes = disaster; atomics need none).
// Valid-prefix skip: mask chunk read as 8 broadcast int4; nv = popcount.
// grid: (TS, BB) = 1024 blocks, block: 256 (thread owns 4 consecutive f).
// ---------------------------------------------------------------------------
__global__ __launch_bounds__(256) void k1_colsum(const float4* __restrict__ x4,
                                                 const int* __restrict__ mask,
                                                 float* __restrict__ ksum) {
    const int ts  = blockIdx.x;
    const int b   = blockIdx.y;
    const int tid = threadIdx.x;

    const int4* mrow = (const int4*)(mask + (size_t)b * TT + ts * TCHUNK);
    int nv = 0;
    #pragma unroll
    for (int i = 0; i < TCHUNK / 4; ++i) {
        int4 m = mrow[i];                     // broadcast load
        nv += m.x + m.y + m.z + m.w;
    }
    if (nv == 0) return;                      // dead chunk: no reads, no atomics

    const float4* xb = x4 + ((size_t)b * TT + (size_t)ts * TCHUNK) * F4 + tid;
    float4 acc = make_float4(0.f, 0.f, 0.f, 0.f);
    #pragma unroll 8
    for (int t = 0; t < nv; ++t) {            // prefix => plain adds
        float4 v = xb[(size_t)t * F4];
        acc.x += v.x; acc.y += v.y; acc.z += v.z; acc.w += v.w;
    }

    float* dst = ksum + (size_t)b * FF + tid * 4;
    atomicAdd(dst + 0, acc.x);                // no-return global_atomic_add_f32
    atomicAdd(dst + 1, acc.y);
    atomicAdd(dst + 2, acc.z);
    atomicAdd(dst + 3, acc.w);
}

// ---------------------------------------------------------------------------
// Kernel 2: gate + apply with self-contained stats prologue (absorbs old k2):
// per block: L from mask (16 KB L2-hot), k = ksum/L into registers, per-wave
// shuffle-reduce Sk=sum(k), Skk=sum(k^2) (each wave holds the full 1024-wide
// k row). Then the R3-proven 4-rows-per-wave gate loop:
//   num = dot(x,k) - mean(x)*Sk ; qd^2 = sum(x^2) - sum(x)^2/F ;
//   kd^2 = Skk - Sk^2/F ; A = 1 - sigmoid(num/(qd*kd)).
// Nontemporal out stores. grid: (TT/16, BB) = 2048 blocks, block: 256.
// ---------------------------------------------------------------------------
__global__ __launch_bounds__(256) void k3_apply(const float4* __restrict__ x4,
                                                const int* __restrict__ mask,
                                                const float4* __restrict__ ksum4,
                                                float4* __restrict__ out4) {
    __shared__ float Lred[4];
    const int tid  = threadIdx.x;
    const int wave = tid >> 6;
    const int lane = tid & 63;
    const int b    = blockIdx.y;

    // ---- valid length L (coalesced 16 KB, L2/L3-hot after k1) ----
    int c = 0;
    #pragma unroll
    for (int i = 0; i < 16; ++i) c += mask[(size_t)b * TT + tid + i * 256];
    float fc = (float)c;
    #pragma unroll
    for (int off = 32; off; off >>= 1) fc += __shfl_xor(fc, off);
    if (lane == 0) Lred[wave] = fc;
    __syncthreads();
    const float Lf   = Lred[0] + Lred[1] + Lred[2] + Lred[3];
    const float invL = 1.0f / Lf;

    // ---- k row into registers (wave covers all 1024 channels) ----
    const float4* krow = ksum4 + (size_t)b * F4;
    float4 kv[4];
    #pragma unroll
    for (int j = 0; j < 4; ++j) {
        kv[j] = krow[lane + 64 * j];
        kv[j].x *= invL; kv[j].y *= invL; kv[j].z *= invL; kv[j].w *= invL;
    }

    // ---- Sk, Skk: per-wave shuffle reduce over the full k row ----
    float a = 0.f, q = 0.f;
    #pragma unroll
    for (int j = 0; j < 4; ++j) {
        a += kv[j].x + kv[j].y + kv[j].z + kv[j].w;
        q = fmaf(kv[j].x, kv[j].x, fmaf(kv[j].y, kv[j].y,
            fmaf(kv[j].z, kv[j].z, fmaf(kv[j].w, kv[j].w, q))));
    }
    #pragma unroll
    for (int off = 32; off; off >>= 1) {
        a += __shfl_xor(a, off);
        q += __shfl_xor(q, off);
    }
    const float sk = a;
    const float kd = sqrtf(fmaxf(q - sk * sk * (1.0f / FF), 0.f));

    // ---- gate + apply: 4 rows per wave, prefetch-pipelined ----
    const int rowbase = blockIdx.x * 16 + wave * 4;
    const size_t base = ((size_t)b * TT + rowbase) * F4;

    const int4 m4 = *(const int4*)(mask + (size_t)b * TT + rowbase);
    const int  nv = m4.x + m4.y + m4.z + m4.w;     // prefix => count

    for (int i = nv; i < 4; ++i) {                 // padded rows: zero, no reads
        vfloat4* orow = (vfloat4*)(out4 + base + (size_t)i * F4);
        vfloat4 z = (vfloat4)(0.f);
        #pragma unroll
        for (int j = 0; j < 4; ++j)
            __builtin_nontemporal_store(z, orow + lane + 64 * j);
    }
    if (nv == 0) return;

    float4 xn[4];
    #pragma unroll
    for (int j = 0; j < 4; ++j) xn[j] = (x4 + base)[lane + 64 * j];

    for (int i = 0; i < nv; ++i) {
        float4 xv[4];
        #pragma unroll
        for (int j = 0; j < 4; ++j) xv[j] = xn[j];
        if (i + 1 < nv) {
            const float4* xrow = x4 + base + (size_t)(i + 1) * F4;
            #pragma unroll
            for (int j = 0; j < 4; ++j) xn[j] = xrow[lane + 64 * j];
        }

        float s1 = 0.f, s2 = 0.f, s3 = 0.f;
        #pragma unroll
        for (int j = 0; j < 4; ++j) {
            s1 += xv[j].x + xv[j].y + xv[j].z + xv[j].w;
            s2 = fmaf(xv[j].x, xv[j].x, fmaf(xv[j].y, xv[j].y,
                 fmaf(xv[j].z, xv[j].z, fmaf(xv[j].w, xv[j].w, s2))));
            s3 = fmaf(xv[j].x, kv[j].x, fmaf(xv[j].y, kv[j].y,
                 fmaf(xv[j].z, kv[j].z, fmaf(xv[j].w, kv[j].w, s3))));
        }
        #pragma unroll
        for (int off = 32; off; off >>= 1) {
            s1 += __shfl_xor(s1, off);
            s2 += __shfl_xor(s2, off);
            s3 += __shfl_xor(s3, off);
        }

        const float mx  = s1 * (1.0f / FF);
        const float num = s3 - mx * sk;                       // dot(x_c, k_c)
        const float qd  = sqrtf(fmaxf(s2 - s1 * s1 * (1.0f / FF), 0.f));
        const float C   = num / (qd * kd);
        const float A   = 1.0f / (1.0f + __expf(C));          // 1 - sigmoid

        vfloat4* orow = (vfloat4*)(out4 + base + (size_t)i * F4);
        #pragma unroll
        for (int j = 0; j < 4; ++j) {
            vfloat4 o;
            o.x = xv[j].x * A; o.y = xv[j].y * A;
            o.z = xv[j].z * A; o.w = xv[j].w * A;
            __builtin_nontemporal_store(o, orow + lane + 64 * j);
        }
    }
}

// ---------------------------------------------------------------------------
extern "C" void kernel_launch(void* const* d_in, const int* in_sizes, int n_in,
                              void* d_out, int out_size, void* d_ws, size_t ws_size,
                              hipStream_t stream) {
    const float* x    = (const float*)d_in[0];
    const int*   mask = (const int*)d_in[1];
    float*       out  = (float*)d_out;

    // workspace (floats): ksum[B*F] (atomic accumulation target)
    float* ksum = (float*)d_ws;

    hipMemsetAsync(ksum, 0, (size_t)BB * FF * sizeof(float), stream);  // ws poisoned

    k1_colsum<<<dim3(TS, BB), 256, 0, stream>>>((const float4*)x, mask, ksum);
    k3_apply<<<dim3(TT / 16, BB), 256, 0, stream>>>((const float4*)x, mask,
                                                    (const float4*)ksum,
                                                    (float4*)out);
}